// Round 7
// baseline (376.722 us; speedup 1.0000x reference)
//
#include <hip/hip_runtime.h>
#include <math.h>
#include <stdint.h>

#define S_LEN   512
#define HORIZON 64
#define T_LEN   (S_LEN + HORIZON)
#define F_IN    4
#define IN_DIM  36   // F_IN + E
#define HID     32

typedef float v4f __attribute__((ext_vector_type(4)));
typedef short v8s __attribute__((ext_vector_type(8)));

__device__ __forceinline__ float frcp(float x) { return __builtin_amdgcn_rcpf(x); }
__device__ __forceinline__ float fsig(float x) { return frcp(1.f + __expf(-x)); }
__device__ __forceinline__ float ftanh(float x) {
    float e = __expf(2.f * x);
    return (e - 1.f) * frcp(e + 1.f);
}
__device__ __forceinline__ float rdlane(float v, int l) {
    return __int_as_float(__builtin_amdgcn_readlane(__float_as_int(v), l));
}
// bf16 pack helpers: {lo,hi} f32 -> one dword of two bf16
__device__ __forceinline__ uint32_t rne16(float f) {
    uint32_t u = __float_as_uint(f);
    return u + 0x7fffu + ((u >> 16) & 1u);
}
__device__ __forceinline__ uint32_t bfpack_rne(float lo, float hi) {
    return __builtin_amdgcn_perm(rne16(hi), rne16(lo), 0x07060302u);
}
__device__ __forceinline__ uint32_t bfpack_fast(float lo, float hi) {   // round-half-up
    return __builtin_amdgcn_perm(__float_as_uint(hi) + 0x8000u,
                                 __float_as_uint(lo) + 0x8000u, 0x07060302u);
}

#define DPP0(x, ctrl, rmask, bmask, bc) \
    __int_as_float(__builtin_amdgcn_update_dpp(0, __float_as_int(x), (ctrl), (rmask), (bmask), (bc)))

union BF { uint32_t u[4]; v8s s; };

// ============ Kernel 1: the sequential recurrence (one wave) ============
// MFMA layout: A[m=lane&15][k=8*(lane>>4)+j] = h[k] (rows replicated),
// B[k][n=lane&15] = W_hh[row(b,n)][k].  D col=lane&15, row=(lane>>4)*4+reg
// (rows replicated -> reg0 valid everywhere). MFMA b: gate q=b>>1 (i,f,g,o),
// unit = n (b even) or n+16 (b odd). Lane (quad,n) owns units n and n+16.
__global__ __launch_bounds__(64, 1) void deepar_seq(
    const float* __restrict__ X,    const float* __restrict__ y,
    const float* __restrict__ Xf,   const float* __restrict__ eps,
    const float* __restrict__ W_ye, const float* __restrict__ b_ye,
    const float* __restrict__ W_ih, const float* __restrict__ W_hh,
    const float* __restrict__ b_ih, const float* __restrict__ b_hh,
    const float* __restrict__ W_ef, const float* __restrict__ b_ef,
    const float* __restrict__ W_av, const float* __restrict__ b_av,
    const float* __restrict__ W_out, const float* __restrict__ b_out,
    const float* __restrict__ W_mu, const float* __restrict__ b_mu,
    const float* __restrict__ W_sig, const float* __restrict__ b_sig,
    float* __restrict__ out, float* __restrict__ hist)
{
    const int lane = threadIdx.x;
    const int quad = lane >> 4;
    const int n    = lane & 15;
    const int j    = lane >> 1;
    const int p    = lane & 1;

    // ---- LDS staging of all per-step inputs + h broadcast line ----
    __shared__ __align__(16) float Xall[T_LEN * F_IN];
    __shared__ __align__(16) float ys[S_LEN];
    __shared__ __align__(16) float epss[T_LEN];
    __shared__ __align__(16) float h_lds[HID];

#pragma unroll
    for (int k = 0; k < 8; ++k)
        ((float4*)Xall)[lane + 64 * k] = ((const float4*)X)[lane + 64 * k];
    ((float4*)Xall)[512 + lane] = ((const float4*)Xf)[lane];
#pragma unroll
    for (int k = 0; k < 2; ++k)
        ((float4*)ys)[lane + 64 * k] = ((const float4*)y)[lane + 64 * k];
#pragma unroll
    for (int k = 0; k < 2; ++k)
        ((float4*)epss)[lane + 64 * k] = ((const float4*)eps)[lane + 64 * k];
    if (lane < 16)
        ((float4*)epss)[lane + 128] = ((const float4*)eps)[lane + 128];
    if (lane < HID) h_lds[lane] = 0.f;

    // ---- B fragments (bf16 RNE) + per-row extras weights ----
    BF bfr[8];
    float wx[8][4], u_r[8], bias_r[8];
#pragma unroll
    for (int b = 0; b < 8; ++b) {
        const int row = 32 * (b >> 1) + n + 16 * (b & 1);
        const float4 wA = ((const float4*)(W_hh + row * HID + 8 * quad))[0];
        const float4 wB = ((const float4*)(W_hh + row * HID + 8 * quad))[1];
        bfr[b].u[0] = bfpack_rne(wA.x, wA.y);  bfr[b].u[1] = bfpack_rne(wA.z, wA.w);
        bfr[b].u[2] = bfpack_rne(wB.x, wB.y);  bfr[b].u[3] = bfpack_rne(wB.z, wB.w);
        const float4 wxv = *((const float4*)(W_ih + row * IN_DIM));
        wx[b][0] = wxv.x; wx[b][1] = wxv.y; wx[b][2] = wxv.z; wx[b][3] = wxv.w;
        float u = 0.f, bb = b_ih[row] + b_hh[row];
        for (int k = 0; k < 32; ++k) {
            const float w = W_ih[row * IN_DIM + 4 + k];
            u  += W_ye[k] * w;
            bb += b_ye[k] * w;
        }
        u_r[b] = u; bias_r[b] = bb;
    }

    // ---- collapsed-attention constants (uniform values) ----
    float A = 0.f, B = 0.f, C1 = 0.f, C2 = 0.f, C3 = 0.f, C4 = 0.f;
#pragma unroll
    for (int k = 0; k < 32; ++k) {
        const float wef = W_ef[k], bef = b_ef[k], wav = W_av[k];
        A  += wef * wav;           B  += bef * wav;
        C1 += wef * W_out[k];      C2 += bef * W_out[k];
        C3 += wef * W_out[32 + k]; C4 += bef * W_out[32 + k];
    }
    B  += b_av[0];
    C2 += b_out[0];
    const float bmu  = b_mu[0], bsig = b_sig[0];
    const float wmu_l  = p ? 0.f : W_mu[j];
    const float wsig_l = p ? 0.f : W_sig[j];

    __syncthreads();

    float h_lo = 0.f, h_hi = 0.f, c_lo = 0.f, c_hi = 0.f;
    const v4f zacc = {0.f, 0.f, 0.f, 0.f};

#define GATE_STEP(YV)                                                          \
    float gv[8];                                                               \
    {                                                                          \
        h_lds[n] = h_lo; h_lds[n + 16] = h_hi;                                 \
        const float4* hb = (const float4*)(h_lds + 8 * quad);                  \
        const float4 ha = hb[0], hc = hb[1];                                   \
        BF af;                                                                 \
        af.u[0] = bfpack_fast(ha.x, ha.y);  af.u[1] = bfpack_fast(ha.z, ha.w); \
        af.u[2] = bfpack_fast(hc.x, hc.y);  af.u[3] = bfpack_fast(hc.z, hc.w); \
        v4f d[8];                                                              \
        _Pragma("unroll")                                                      \
        for (int b = 0; b < 8; ++b)                                            \
            d[b] = __builtin_amdgcn_mfma_f32_16x16x32_bf16(af.s, bfr[b].s,     \
                                                           zacc, 0, 0, 0);     \
        _Pragma("unroll")                                                      \
        for (int b = 0; b < 8; ++b)                                            \
            gv[b] = d[b][0] + fmaf(u_r[b], (YV), bias_r[b]) +                  \
                    (fmaf(wx[b][0], xv.x, wx[b][1] * xv.y) +                   \
                     fmaf(wx[b][2], xv.z, wx[b][3] * xv.w));                   \
    }                                                                          \
    {                                                                          \
        const float si = fsig(gv[0]), sf = fsig(gv[2]),                        \
                    tg = ftanh(gv[4]), so = fsig(gv[6]);                       \
        c_lo = sf * c_lo + si * tg;                                            \
        h_lo = so * ftanh(c_lo);                                               \
    }                                                                          \
    {                                                                          \
        const float si = fsig(gv[1]), sf = fsig(gv[3]),                        \
                    tg = ftanh(gv[5]), so = fsig(gv[7]);                       \
        c_hi = sf * c_hi + si * tg;                                            \
        h_hi = so * ftanh(c_hi);                                               \
    }

    // ---------- Phase A: t = 0..510 — LSTM cell only; outputs deferred ----------
#pragma unroll 2
    for (int t = 0; t < S_LEN - 1; ++t) {
        const float4 xv = ((const float4*)Xall)[t];
        const float  yt = ys[t];
        GATE_STEP(yt);
        if (lane < 16) {                      // quad 0 publishes (all quads identical)
            hist[t * HID + n]      = h_lo;
            hist[t * HID + n + 16] = h_hi;
        }
    }

    // ---------- Phase B: t = 511..575 — full step (feedback needed) ----------
    float ynext = 0.f;
    const float y511 = ys[S_LEN - 1];
#pragma unroll 1
    for (int t = S_LEN - 1; t < T_LEN; ++t) {
        const float4 xv   = ((const float4*)Xall)[t];
        const float eps_t = epss[t];
        const float yin   = (t == S_LEN - 1) ? y511 : ynext;
        GATE_STEP(yin);

        // publish new h, then run the attention tail in even-lane convention
        h_lds[n] = h_lo; h_lds[n + 16] = h_hi;
        const float hj = h_lds[j];

        const float av   = __expf(hj * A + B);
        const float av_e = p ? 0.f : av;
        const float avh  = av_e * hj;
        float sP = av_e, sQ = avh;
        sP += DPP0(sP, 0x112, 0xF, 0xF, true);  sQ += DPP0(sQ, 0x112, 0xF, 0xF, true);
        sP += DPP0(sP, 0x114, 0xF, 0xF, true);  sQ += DPP0(sQ, 0x114, 0xF, 0xF, true);
        sP += DPP0(sP, 0x118, 0xF, 0xF, true);  sQ += DPP0(sQ, 0x118, 0xF, 0xF, true);
        float tP = DPP0(sP, 0x111, 0xF, 0xF, true), tQ = DPP0(sQ, 0x111, 0xF, 0xF, true);
        sP += DPP0(tP, 0x142, 0xA, 0xF, true);  sQ += DPP0(tQ, 0x142, 0xA, 0xF, true);
        tP = DPP0(sP, 0x111, 0xF, 0xF, true);   tQ = DPP0(sQ, 0x111, 0xF, 0xF, true);
        sP += DPP0(tP, 0x143, 0xC, 0xF, true);  sQ += DPP0(tQ, 0x143, 0xC, 0xF, true);

        const float P = sP - av_e, Q = sQ - avh;
        const float rden = frcp(P + 1e-9f);
        const float outv = ftanh(hj * C1 + C2 + (Q * C3 + P * C4) * rden);

        float pm = outv * wmu_l, ps = outv * wsig_l;
        pm += DPP0(pm, 0xB1,  0xF, 0xF, false);  ps += DPP0(ps, 0xB1,  0xF, 0xF, false);
        pm += DPP0(pm, 0x4E,  0xF, 0xF, false);  ps += DPP0(ps, 0x4E,  0xF, 0xF, false);
        pm += DPP0(pm, 0x141, 0xF, 0xF, false);  ps += DPP0(ps, 0x141, 0xF, 0xF, false);
        pm += DPP0(pm, 0x140, 0xF, 0xF, false);  ps += DPP0(ps, 0x140, 0xF, 0xF, false);
        pm += DPP0(pm, 0x142, 0xA, 0xF, true);   ps += DPP0(ps, 0x142, 0xA, 0xF, true);
        pm += DPP0(pm, 0x143, 0xC, 0xF, true);   ps += DPP0(ps, 0x143, 0xC, 0xF, true);

        const float mu    = rdlane(pm, 63) + bmu;
        const float sigma = __logf(1.f + __expf(rdlane(ps, 63) + bsig)) + 1e-6f;
        const float ynew  = mu + sigma * eps_t;
        ynext = ynew;

        if (lane == 0) {
            out[HORIZON + t]         = mu;
            out[HORIZON + T_LEN + t] = sigma;
            if (t >= S_LEN - 1 && t < S_LEN - 1 + HORIZON)
                out[t - (S_LEN - 1)] = ynew;
        }
    }
#undef GATE_STEP
}

// ============ Kernel 2: parallel deferred outputs for t = 0..510 ============
__global__ __launch_bounds__(256) void deepar_par(
    const float* __restrict__ hist,
    const float* __restrict__ W_ef, const float* __restrict__ b_ef,
    const float* __restrict__ W_av, const float* __restrict__ b_av,
    const float* __restrict__ W_out, const float* __restrict__ b_out,
    const float* __restrict__ W_mu, const float* __restrict__ b_mu,
    const float* __restrict__ W_sig, const float* __restrict__ b_sig,
    float* __restrict__ out)
{
    const int gid = (blockIdx.x * 256 + threadIdx.x) >> 5;   // one step per 32 lanes
    const int l   = threadIdx.x & 31;
    if (gid >= S_LEN - 1) return;

    float A = 0.f, B = 0.f, C1 = 0.f, C2 = 0.f, C3 = 0.f, C4 = 0.f;
#pragma unroll
    for (int k = 0; k < 32; ++k) {
        const float wef = W_ef[k], bef = b_ef[k], wav = W_av[k];
        A  += wef * wav;           B  += bef * wav;
        C1 += wef * W_out[k];      C2 += bef * W_out[k];
        C3 += wef * W_out[32 + k]; C4 += bef * W_out[32 + k];
    }
    B  += b_av[0];
    C2 += b_out[0];

    const float hj  = hist[gid * HID + l];
    const float av  = __expf(hj * A + B);
    const float avh = av * hj;
    float sP = av, sQ = avh;
#pragma unroll
    for (int d = 1; d < 32; d <<= 1) {
        const float pP = __shfl_up(sP, d, 32);
        const float pQ = __shfl_up(sQ, d, 32);
        if (l >= d) { sP += pP; sQ += pQ; }
    }
    const float P = sP - av, Q = sQ - avh;
    const float rden = frcp(P + 1e-9f);
    const float ex = __expf(2.f * (hj * C1 + C2 + (Q * C3 + P * C4) * rden));
    const float outv = (ex - 1.f) * frcp(ex + 1.f);

    float pm = outv * W_mu[l], ps = outv * W_sig[l];
#pragma unroll
    for (int m = 16; m >= 1; m >>= 1) {
        pm += __shfl_xor(pm, m, 32);
        ps += __shfl_xor(ps, m, 32);
    }
    if (l == 0) {
        out[HORIZON + gid]         = pm + b_mu[0];
        out[HORIZON + T_LEN + gid] = __logf(1.f + __expf(ps + b_sig[0])) + 1e-6f;
    }
}

extern "C" void kernel_launch(void* const* d_in, const int* in_sizes, int n_in,
                              void* d_out, int out_size, void* d_ws, size_t ws_size,
                              hipStream_t stream) {
    float* hist = (float*)d_ws;   // (S_LEN-1) x HID floats

    deepar_seq<<<1, 64, 0, stream>>>(
        (const float*)d_in[0],  (const float*)d_in[1],  (const float*)d_in[2],
        (const float*)d_in[3],  (const float*)d_in[4],  (const float*)d_in[5],
        (const float*)d_in[6],  (const float*)d_in[7],  (const float*)d_in[8],
        (const float*)d_in[9],  (const float*)d_in[10], (const float*)d_in[11],
        (const float*)d_in[12], (const float*)d_in[13], (const float*)d_in[14],
        (const float*)d_in[15], (const float*)d_in[16], (const float*)d_in[17],
        (const float*)d_in[18], (const float*)d_in[19], (float*)d_out, hist);

    const int groups = S_LEN - 1;
    const int blocks = (groups * 32 + 255) / 256;
    deepar_par<<<blocks, 256, 0, stream>>>(
        hist,
        (const float*)d_in[10], (const float*)d_in[11],
        (const float*)d_in[12], (const float*)d_in[13],
        (const float*)d_in[14], (const float*)d_in[15],
        (const float*)d_in[16], (const float*)d_in[17],
        (const float*)d_in[18], (const float*)d_in[19], (float*)d_out);
}

// Round 8
// 256.736 us; speedup vs baseline: 1.4674x; 1.4674x over previous
//
#include <hip/hip_runtime.h>
#include <math.h>
#include <stdint.h>

#define S_LEN   512
#define HORIZON 64
#define T_LEN   (S_LEN + HORIZON)
#define F_IN    4
#define IN_DIM  36   // F_IN + E
#define HID     32

__device__ __forceinline__ float frcp(float x) { return __builtin_amdgcn_rcpf(x); }
__device__ __forceinline__ float fsig(float x) { return frcp(1.f + __expf(-x)); }
__device__ __forceinline__ float ftanh(float x) {
    float e = __expf(2.f * x);
    return (e - 1.f) * frcp(e + 1.f);
}
__device__ __forceinline__ float rdlane(float v, int l) {
    return __int_as_float(__builtin_amdgcn_readlane(__float_as_int(v), l));
}
// f16 dot2 with f32 accumulate: acc += a.h[0]*b.h[0] + a.h[1]*b.h[1]
__device__ __forceinline__ void dot2(float& acc, uint32_t a, uint32_t b) {
    asm("v_dot2_f32_f16 %0, %1, %2, %0" : "+v"(acc) : "v"(a), "v"(b));
}

#define DPP0(x, ctrl, rmask, bmask, bc) \
    __int_as_float(__builtin_amdgcn_update_dpp(0, __float_as_int(x), (ctrl), (rmask), (bmask), (bc)))
#define SWAP1(x) DPP0((x), 0xB1, 0xF, 0xF, false)   // quad_perm [1,0,3,2]: lane 2j <-> 2j+1

union PK { _Float16 f[2]; uint32_t u; };

// ============ Kernel 1: the sequential recurrence (one wave) ============
// Interleaved layout: lane 2j+p: p==0 -> rows i[j], g[j]; p==1 -> rows f[j], o[j].
// Both parities reconstruct identical c,h each step (quad-perm exchange), so
// h is valid in ALL lanes: unconditional LDS publish, register h for phase B.
__global__ __launch_bounds__(64, 1) void deepar_seq(
    const float* __restrict__ X,    const float* __restrict__ y,
    const float* __restrict__ Xf,   const float* __restrict__ eps,
    const float* __restrict__ W_ye, const float* __restrict__ b_ye,
    const float* __restrict__ W_ih, const float* __restrict__ W_hh,
    const float* __restrict__ b_ih, const float* __restrict__ b_hh,
    const float* __restrict__ W_ef, const float* __restrict__ b_ef,
    const float* __restrict__ W_av, const float* __restrict__ b_av,
    const float* __restrict__ W_out, const float* __restrict__ b_out,
    const float* __restrict__ W_mu, const float* __restrict__ b_mu,
    const float* __restrict__ W_sig, const float* __restrict__ b_sig,
    float* __restrict__ out, float* __restrict__ hist2)
{
    const int lane = threadIdx.x;
    const int j    = lane >> 1;
    const int p    = lane & 1;
    const int r0   = j + 32 * p;      // i-row (p=0) / f-row (p=1)
    const int r1   = r0 + 64;         // g-row (p=0) / o-row (p=1)

    __shared__ __align__(16) _Float16 h16[HID];   // 64 B: f16 h broadcast line

    // ---- resident weights: W_hh rows packed to f16 pairs ----
    uint32_t wpk0[16], wpk1[16];
#pragma unroll
    for (int k = 0; k < 16; ++k) {
        PK t0, t1;
        t0.f[0] = (_Float16)W_hh[r0 * HID + 2 * k];
        t0.f[1] = (_Float16)W_hh[r0 * HID + 2 * k + 1];
        t1.f[0] = (_Float16)W_hh[r1 * HID + 2 * k];
        t1.f[1] = (_Float16)W_hh[r1 * HID + 2 * k + 1];
        wpk0[k] = t0.u;  wpk1[k] = t1.u;
    }
    // x-part weights (f32) + collapsed y-embedding (u, bias)
    float wx0[4], wx1[4];
#pragma unroll
    for (int k = 0; k < 4; ++k) {
        wx0[k] = W_ih[r0 * IN_DIM + k];
        wx1[k] = W_ih[r1 * IN_DIM + k];
    }
    float u0 = 0.f, u1 = 0.f;
    float bias0 = b_ih[r0] + b_hh[r0], bias1 = b_ih[r1] + b_hh[r1];
#pragma unroll
    for (int k = 0; k < 32; ++k) {
        const float w0 = W_ih[r0 * IN_DIM + 4 + k];
        const float w1 = W_ih[r1 * IN_DIM + 4 + k];
        u0 += W_ye[k] * w0;  bias0 += b_ye[k] * w0;
        u1 += W_ye[k] * w1;  bias1 += b_ye[k] * w1;
    }

    // ---- collapsed-attention constants (uniform values) ----
    float A = 0.f, B = 0.f, C1 = 0.f, C2 = 0.f, C3 = 0.f, C4 = 0.f;
#pragma unroll
    for (int k = 0; k < 32; ++k) {
        const float wef = W_ef[k], bef = b_ef[k], wav = W_av[k];
        A  += wef * wav;           B  += bef * wav;
        C1 += wef * W_out[k];      C2 += bef * W_out[k];
        C3 += wef * W_out[32 + k]; C4 += bef * W_out[32 + k];
    }
    B  += b_av[0];
    C2 += b_out[0];
    const float bmu  = b_mu[0], bsig = b_sig[0];
    const float wmu_l  = p ? 0.f : W_mu[j];
    const float wsig_l = p ? 0.f : W_sig[j];
    const float sc_a = p ? 1.f : 2.f;     // tanh-via-sigmoid without selects
    const float sc_b = p ? 0.f : -1.f;

    float h = 0.f, c = 0.f;

#define GATE_STEP(XV, YT, G0, G1)                                              \
    {                                                                          \
        float gx0 = fmaf(u0, (YT), bias0);                                     \
        gx0 = fmaf(wx0[0], (XV).x, gx0); gx0 = fmaf(wx0[1], (XV).y, gx0);      \
        gx0 = fmaf(wx0[2], (XV).z, gx0); gx0 = fmaf(wx0[3], (XV).w, gx0);      \
        float gx1 = fmaf(u1, (YT), bias1);                                     \
        gx1 = fmaf(wx1[0], (XV).x, gx1); gx1 = fmaf(wx1[1], (XV).y, gx1);      \
        gx1 = fmaf(wx1[2], (XV).z, gx1); gx1 = fmaf(wx1[3], (XV).w, gx1);      \
        h16[j] = (_Float16)h;              /* pairs write same value/addr */   \
        asm volatile("" ::: "memory");                                         \
        const uint4 q0 = ((const uint4*)h16)[0], q1 = ((const uint4*)h16)[1];  \
        const uint4 q2 = ((const uint4*)h16)[2], q3 = ((const uint4*)h16)[3];  \
        float a0 = gx0, a1 = 0.f, a2 = 0.f, a3 = 0.f;                          \
        dot2(a0, wpk0[0],  q0.x); dot2(a0, wpk0[1],  q0.y);                    \
        dot2(a0, wpk0[2],  q0.z); dot2(a0, wpk0[3],  q0.w);                    \
        dot2(a1, wpk0[4],  q1.x); dot2(a1, wpk0[5],  q1.y);                    \
        dot2(a1, wpk0[6],  q1.z); dot2(a1, wpk0[7],  q1.w);                    \
        dot2(a2, wpk0[8],  q2.x); dot2(a2, wpk0[9],  q2.y);                    \
        dot2(a2, wpk0[10], q2.z); dot2(a2, wpk0[11], q2.w);                    \
        dot2(a3, wpk0[12], q3.x); dot2(a3, wpk0[13], q3.y);                    \
        dot2(a3, wpk0[14], q3.z); dot2(a3, wpk0[15], q3.w);                    \
        float b0 = gx1, b1 = 0.f, b2 = 0.f, b3 = 0.f;                          \
        dot2(b0, wpk1[0],  q0.x); dot2(b0, wpk1[1],  q0.y);                    \
        dot2(b0, wpk1[2],  q0.z); dot2(b0, wpk1[3],  q0.w);                    \
        dot2(b1, wpk1[4],  q1.x); dot2(b1, wpk1[5],  q1.y);                    \
        dot2(b1, wpk1[6],  q1.z); dot2(b1, wpk1[7],  q1.w);                    \
        dot2(b2, wpk1[8],  q2.x); dot2(b2, wpk1[9],  q2.y);                    \
        dot2(b2, wpk1[10], q2.z); dot2(b2, wpk1[11], q2.w);                    \
        dot2(b3, wpk1[12], q3.x); dot2(b3, wpk1[13], q3.y);                    \
        dot2(b3, wpk1[14], q3.z); dot2(b3, wpk1[15], q3.w);                    \
        G0 = (a0 + a1) + (a2 + a3);                                            \
        G1 = (b0 + b1) + (b2 + b3);                                            \
    }

#define STEP_NONLIN(G0, G1)                                                    \
    {                                                                          \
        const float s0 = fsig(G0);               /* sig(i) even / sig(f) odd */\
        const float sg = fsig((G1) * sc_a);                                    \
        const float s1 = fmaf(sg, sc_a, sc_b);   /* tanh(g) even / sig(o) odd*/\
        const float prod = s0 * s1;                                            \
        const float s0x   = SWAP1(s0);                                         \
        const float prodx = SWAP1(prod);                                       \
        const float s1x   = SWAP1(s1);                                         \
        const float fall = p ? s0 : s0x;         /* sig(f) everywhere */       \
        const float ig   = p ? prodx : prod;     /* sig(i)*tanh(g) */          \
        const float oall = p ? s1 : s1x;         /* sig(o) everywhere */       \
        c = fmaf(fall, c, ig);                                                 \
        h = oall * ftanh(c);                     /* identical in all lanes */  \
    }

    // ---------- Phase A: t = 0..510 — LSTM cell only; outputs deferred ----------
    float4 xc = ((const float4*)X)[0];  float yc = y[0];
    float4 xn = ((const float4*)X)[1];  float yn = y[1];
#pragma unroll 2
    for (int t = 0; t < S_LEN - 1; ++t) {
        const int tp = (t + 2 < S_LEN) ? t + 2 : S_LEN - 1;
        const float4 xf = ((const float4*)X)[tp];
        const float  yf = y[tp];

        float g0, g1;
        GATE_STEP(xc, yc, g0, g1);
        STEP_NONLIN(g0, g1);

        hist2[t * 64 + lane] = h;

        xc = xn; yc = yn; xn = xf; yn = yf;
    }

    // ---------- Phase B: t = 511..575 — full step (feedback needed) ----------
    float ynext = 0.f;
    const float y511 = y[S_LEN - 1];
    float4 xb = ((const float4*)X)[S_LEN - 1];
    float  eb = eps[S_LEN - 1];
#pragma unroll 1
    for (int t = S_LEN - 1; t < T_LEN; ++t) {
        const int tp = (t + 1 < T_LEN) ? t + 1 : T_LEN - 1;
        const float* src = (tp < S_LEN) ? (X + tp * F_IN) : (Xf + (tp - S_LEN) * F_IN);
        const float4 xf = *(const float4*)src;
        const float  ef = eps[tp];

        const float yin = (t == S_LEN - 1) ? y511 : ynext;
        float g0, g1;
        GATE_STEP(xb, yin, g0, g1);
        STEP_NONLIN(g0, g1);

        // collapsed attention: h valid in registers for all lanes (unit j)
        const float av   = __expf(h * A + B);
        const float av_e = p ? 0.f : av;
        const float avh  = av_e * h;
        float sP = av_e, sQ = avh;
        sP += DPP0(sP, 0x112, 0xF, 0xF, true);  sQ += DPP0(sQ, 0x112, 0xF, 0xF, true);
        sP += DPP0(sP, 0x114, 0xF, 0xF, true);  sQ += DPP0(sQ, 0x114, 0xF, 0xF, true);
        sP += DPP0(sP, 0x118, 0xF, 0xF, true);  sQ += DPP0(sQ, 0x118, 0xF, 0xF, true);
        float tP = DPP0(sP, 0x111, 0xF, 0xF, true), tQ = DPP0(sQ, 0x111, 0xF, 0xF, true);
        sP += DPP0(tP, 0x142, 0xA, 0xF, true);  sQ += DPP0(tQ, 0x142, 0xA, 0xF, true);
        tP = DPP0(sP, 0x111, 0xF, 0xF, true);   tQ = DPP0(sQ, 0x111, 0xF, 0xF, true);
        sP += DPP0(tP, 0x143, 0xC, 0xF, true);  sQ += DPP0(tQ, 0x143, 0xC, 0xF, true);

        const float P = sP - av_e, Q = sQ - avh;
        const float rden = frcp(P + 1e-9f);
        const float outv = ftanh(h * C1 + C2 + (Q * C3 + P * C4) * rden);

        // mu / sigma: DPP tree-reduce, total in lane 63
        float pm = outv * wmu_l, ps = outv * wsig_l;
        pm += SWAP1(pm);                         ps += SWAP1(ps);
        pm += DPP0(pm, 0x4E,  0xF, 0xF, false);  ps += DPP0(ps, 0x4E,  0xF, 0xF, false);
        pm += DPP0(pm, 0x141, 0xF, 0xF, false);  ps += DPP0(ps, 0x141, 0xF, 0xF, false);
        pm += DPP0(pm, 0x140, 0xF, 0xF, false);  ps += DPP0(ps, 0x140, 0xF, 0xF, false);
        pm += DPP0(pm, 0x142, 0xA, 0xF, true);   ps += DPP0(ps, 0x142, 0xA, 0xF, true);
        pm += DPP0(pm, 0x143, 0xC, 0xF, true);   ps += DPP0(ps, 0x143, 0xC, 0xF, true);

        const float mu    = rdlane(pm, 63) + bmu;
        const float sigma = __logf(1.f + __expf(rdlane(ps, 63) + bsig)) + 1e-6f;
        const float ynew  = mu + sigma * eb;
        ynext = ynew;

        if (lane == 0) {
            out[HORIZON + t]         = mu;
            out[HORIZON + T_LEN + t] = sigma;
            if (t >= S_LEN - 1 && t < S_LEN - 1 + HORIZON)
                out[t - (S_LEN - 1)] = ynew;
        }

        xb = xf; eb = ef;
    }
#undef GATE_STEP
#undef STEP_NONLIN
}

// ============ Kernel 2: parallel deferred outputs for t = 0..510 ============
__global__ __launch_bounds__(256) void deepar_par(
    const float* __restrict__ hist2,
    const float* __restrict__ W_ef, const float* __restrict__ b_ef,
    const float* __restrict__ W_av, const float* __restrict__ b_av,
    const float* __restrict__ W_out, const float* __restrict__ b_out,
    const float* __restrict__ W_mu, const float* __restrict__ b_mu,
    const float* __restrict__ W_sig, const float* __restrict__ b_sig,
    float* __restrict__ out)
{
    const int gid = (blockIdx.x * 256 + threadIdx.x) >> 5;   // one step per 32 lanes
    const int l   = threadIdx.x & 31;
    if (gid >= S_LEN - 1) return;

    float A = 0.f, B = 0.f, C1 = 0.f, C2 = 0.f, C3 = 0.f, C4 = 0.f;
#pragma unroll
    for (int k = 0; k < 32; ++k) {
        const float wef = W_ef[k], bef = b_ef[k], wav = W_av[k];
        A  += wef * wav;           B  += bef * wav;
        C1 += wef * W_out[k];      C2 += bef * W_out[k];
        C3 += wef * W_out[32 + k]; C4 += bef * W_out[32 + k];
    }
    B  += b_av[0];
    C2 += b_out[0];

    const float hj  = hist2[gid * 64 + 2 * l];   // even entries hold h_j
    const float av  = __expf(hj * A + B);
    const float avh = av * hj;
    float sP = av, sQ = avh;
#pragma unroll
    for (int d = 1; d < 32; d <<= 1) {
        const float pP = __shfl_up(sP, d, 32);
        const float pQ = __shfl_up(sQ, d, 32);
        if (l >= d) { sP += pP; sQ += pQ; }
    }
    const float P = sP - av, Q = sQ - avh;
    const float rden = frcp(P + 1e-9f);
    const float ex = __expf(2.f * (hj * C1 + C2 + (Q * C3 + P * C4) * rden));
    const float outv = (ex - 1.f) * frcp(ex + 1.f);

    float pm = outv * W_mu[l], ps = outv * W_sig[l];
#pragma unroll
    for (int m = 16; m >= 1; m >>= 1) {
        pm += __shfl_xor(pm, m, 32);
        ps += __shfl_xor(ps, m, 32);
    }
    if (l == 0) {
        out[HORIZON + gid]         = pm + b_mu[0];
        out[HORIZON + T_LEN + gid] = __logf(1.f + __expf(ps + b_sig[0])) + 1e-6f;
    }
}

extern "C" void kernel_launch(void* const* d_in, const int* in_sizes, int n_in,
                              void* d_out, int out_size, void* d_ws, size_t ws_size,
                              hipStream_t stream) {
    float* hist2 = (float*)d_ws;   // (S_LEN-1) x 64 floats

    deepar_seq<<<1, 64, 0, stream>>>(
        (const float*)d_in[0],  (const float*)d_in[1],  (const float*)d_in[2],
        (const float*)d_in[3],  (const float*)d_in[4],  (const float*)d_in[5],
        (const float*)d_in[6],  (const float*)d_in[7],  (const float*)d_in[8],
        (const float*)d_in[9],  (const float*)d_in[10], (const float*)d_in[11],
        (const float*)d_in[12], (const float*)d_in[13], (const float*)d_in[14],
        (const float*)d_in[15], (const float*)d_in[16], (const float*)d_in[17],
        (const float*)d_in[18], (const float*)d_in[19], (float*)d_out, hist2);

    const int groups = S_LEN - 1;
    const int blocks = (groups * 32 + 255) / 256;
    deepar_par<<<blocks, 256, 0, stream>>>(
        hist2,
        (const float*)d_in[10], (const float*)d_in[11],
        (const float*)d_in[12], (const float*)d_in[13],
        (const float*)d_in[14], (const float*)d_in[15],
        (const float*)d_in[16], (const float*)d_in[17],
        (const float*)d_in[18], (const float*)d_in[19], (float*)d_out);
}